// Round 7
// baseline (587.458 us; speedup 1.0000x reference)
//
#include <hip/hip_runtime.h>
#include <math.h>

// DifferentiableRenderer: B=2 cameras, N=65536 gaussians, 128x128 image.
// R7: dynamic work-stealing. 2048 persistent blocks pull (b,tile,chunk)
// items off a global counter (4096 items, heavy-center tiles ordered first).
// Register accumulators flush via atomics only when (b,tile) changes.
// Cull+compact chunk structure unchanged from R4.

#define HH 128
#define WW 128
#define HWP (HH * WW)
#define TILE_ROWS 16
#define PPT 8            // pixels per thread (one column, stride 2 rows)
#define CHUNK_G 256      // gaussians culled/compacted per item
#define NBLOCKS 2048     // exactly full-device residency (8 blocks/CU)

__global__ void proj_kernel(const float* __restrict__ pos,
                            const float* __restrict__ col,
                            const float* __restrict__ opa,
                            const float* __restrict__ scl,
                            const float* __restrict__ qv,
                            const float* __restrict__ tv,
                            const float* fxp, const float* fyp,
                            const float* cxp, const float* cyp,
                            float4* __restrict__ out, int N, int B) {
    int i = blockIdx.x * blockDim.x + threadIdx.x;
    if (i >= N * B) return;
    int b = i / N;
    int g = i - b * N;

    float qw = qv[b * 4 + 0], qx = qv[b * 4 + 1], qy = qv[b * 4 + 2], qz = qv[b * 4 + 3];
    float qn = rsqrtf(qw * qw + qx * qx + qy * qy + qz * qz);
    qw *= qn; qx *= qn; qy *= qn; qz *= qn;
    float r00 = 1.0f - 2.0f * (qy * qy + qz * qz);
    float r01 = 2.0f * (qx * qy - qz * qw);
    float r02 = 2.0f * (qx * qz + qy * qw);
    float r10 = 2.0f * (qx * qy + qz * qw);
    float r11 = 1.0f - 2.0f * (qx * qx + qz * qz);
    float r12 = 2.0f * (qy * qz - qx * qw);
    float r20 = 2.0f * (qx * qz - qy * qw);
    float r21 = 2.0f * (qy * qz + qx * qw);
    float r22 = 1.0f - 2.0f * (qx * qx + qy * qy);

    float X = pos[g * 3 + 0], Y = pos[g * 3 + 1], Z = pos[g * 3 + 2];
    float pcx = r00 * X + r01 * Y + r02 * Z + tv[b * 3 + 0];
    float pcy = r10 * X + r11 * Y + r12 * Z + tv[b * 3 + 1];
    float pcz = r20 * X + r21 * Y + r22 * Z + tv[b * 3 + 2];

    float px = pcx / pcz * (*fxp) + (*cxp);
    float py = pcy / pcz * (*fyp) + (*cyp);

    float sc = scl[g];
    float var = sc * sc;
    float l = __builtin_amdgcn_logf(opa[g]);        // log2(opacity)
    // w = op*exp(-0.5*d2/var) = exp2(l - (s*dx)^2 - (s*dy)^2), s = sqrt(0.5*log2e)/scale
    float s = 0.84932180028801905f / sc;
    // cull radius: keep terms with w >= 2^-45  (d2 <= (45+l)*var*2ln2)
    float d2max = fmaxf(45.0f + l, 0.0f) * var * 1.38629436111989061f;
    float rad = sqrtf(d2max);

    out[(size_t)(b * N + g) * 2 + 0] = make_float4(px, py, s, rad);
    out[(size_t)(b * N + g) * 2 + 1] = make_float4(col[g * 3 + 0], col[g * 3 + 1], col[g * 3 + 2], l);
}

__global__ void zero_kernel(float* __restrict__ p, int n) {
    int i = blockIdx.x * blockDim.x + threadIdx.x;
    if (i < n) p[i] = 0.0f;     // covers accbuf + work counter
}

#define FLUSH_ACC(BB, YTOP)                                        \
    {                                                              \
        float* ab = accbuf + (size_t)(BB) * HWP * 4;               \
        _Pragma("unroll")                                          \
        for (int p = 0; p < PPT; ++p) {                            \
            int y = (YTOP) + yrow + p * 2;                         \
            int pix = y * WW + x;                                  \
            atomicAdd(ab + pix * 4 + 0, nr[p]);                    \
            atomicAdd(ab + pix * 4 + 1, ng[p]);                    \
            atomicAdd(ab + pix * 4 + 2, nb[p]);                    \
            atomicAdd(ab + pix * 4 + 3, nd[p]);                    \
            nr[p] = 0.0f; ng[p] = 0.0f; nb[p] = 0.0f; nd[p] = 0.0f;\
        }                                                          \
    }

__global__ __launch_bounds__(256) void accum_kernel(const float4* __restrict__ gdata,
                                                    float* __restrict__ accbuf,
                                                    int* __restrict__ workctr,
                                                    int N, int nitems) {
    __shared__ float4 shc[CHUNK_G * 2];   // compacted: (px,py,s,l),(r,g,b,2s)
    __shared__ int wcnt[4];
    __shared__ int witem;
    int tid  = threadIdx.x;
    int x    = tid & 127;
    int yrow = tid >> 7;            // 0 or 1
    int wid  = tid >> 6;
    int lane = tid & 63;
    float xf = (float)x;

    float nr[PPT], ng[PPT], nb[PPT], nd[PPT];
#pragma unroll
    for (int p = 0; p < PPT; ++p) { nr[p] = 0.0f; ng[p] = 0.0f; nb[p] = 0.0f; nd[p] = 0.0f; }

    int nchunks = N / CHUNK_G;      // chunks per (b,tile) = 256
    int cur_tile = -1, cur_b = -1;
    int ytop = 0;
    float ylo = 0.0f, yhi = 0.0f, y0f = 0.0f;

    for (;;) {
        if (tid == 0) witem = atomicAdd(workctr, 1);
        __syncthreads();                   // witem visible; shc safe to reuse
        int w = witem;
        if (w >= nitems) break;
        int chunki = w % nchunks;
        int rest   = w / nchunks;
        int tp     = rest & 7;
        int b      = rest >> 3;
        // heavy center tiles first: perm {3,4,2,5,1,6,0,7}
        int tile = (int)((0x70615243u >> (tp * 4)) & 0xFu);

        if (tile != cur_tile || b != cur_b) {
            if (cur_b >= 0) FLUSH_ACC(cur_b, ytop);     // uses OLD ytop
            cur_tile = tile; cur_b = b;
            ytop = tile * TILE_ROWS;
            ylo  = (float)ytop;
            yhi  = (float)(ytop + TILE_ROWS - 1);
            y0f  = (float)(ytop + yrow);
        }

        // ---- thread-parallel cull: one gaussian per thread (coalesced 32B) ----
        const float4* gbase = gdata + (size_t)b * N * 2;
        int src = (chunki * CHUNK_G + tid) * 2;
        float4 f0 = gbase[src];        // px, py, s, rad
        float4 f1 = gbase[src + 1];    // r, g, b, l
        float px = f0.x, py = f0.y, rad = f0.w;
        bool keep = (py + rad >= ylo) & (py - rad <= yhi) &
                    (px + rad >= 0.0f) & (px - rad <= 127.0f);
        unsigned long long m = __ballot(keep);

        if (lane == 0) wcnt[wid] = __popcll(m);
        __syncthreads();                       // wcnt visible
        int base = 0;
        if (wid > 0) base += wcnt[0];
        if (wid > 1) base += wcnt[1];
        if (wid > 2) base += wcnt[2];
        int total = wcnt[0] + wcnt[1] + wcnt[2] + wcnt[3];
        int pos = base + __popcll(m & ((1ull << lane) - 1ull));
        if (keep) {
            shc[pos * 2]     = make_float4(f0.x, f0.y, f0.z, f1.w);        // px,py,s,l
            shc[pos * 2 + 1] = make_float4(f1.x, f1.y, f1.z, f0.z + f0.z); // r,g,b,2s
        }
        __syncthreads();                       // shc visible

        // ---- branch-free dense loop over survivors (broadcast LDS reads) ----
#pragma unroll 2
        for (int j = 0; j < total; ++j) {
            float4 a0 = shc[j * 2];
            float4 a1 = shc[j * 2 + 1];
            float s   = a0.z;
            float dx  = a0.x - xf;
            float sdx = s * dx;
            float lm  = __builtin_fmaf(-sdx, sdx, a0.w);   // l - sdx^2
            float sdy = s * (a0.y - y0f);
            float s2  = a1.w;                              // 2s
#pragma unroll
            for (int p = 0; p < PPT; ++p) {
                float e = __builtin_fmaf(-sdy, sdy, lm);
                float wv = __builtin_amdgcn_exp2f(e);
                nr[p] = __builtin_fmaf(wv, a1.x, nr[p]);
                ng[p] = __builtin_fmaf(wv, a1.y, ng[p]);
                nb[p] = __builtin_fmaf(wv, a1.z, nb[p]);
                nd[p] += wv;
                sdy -= s2;
            }
        }
    }

    if (cur_b >= 0) FLUSH_ACC(cur_b, ytop);
}

__global__ void final_kernel(const float* __restrict__ accbuf,
                             float* __restrict__ out, int B, float epsadd) {
    int i = blockIdx.x * blockDim.x + threadIdx.x;   // over B*HW
    if (i >= B * HWP) return;
    int b = i / HWP;
    int p = i - b * HWP;
    const float* a = accbuf + (size_t)i * 4;
    float den = fmaxf(a[3] + epsadd, 1e-8f);
    out[(size_t)(b * 3 + 0) * HWP + p] = a[0] / den;
    out[(size_t)(b * 3 + 1) * HWP + p] = a[1] / den;
    out[(size_t)(b * 3 + 2) * HWP + p] = a[2] / den;
}

extern "C" void kernel_launch(void* const* d_in, const int* in_sizes, int n_in,
                              void* d_out, int out_size, void* d_ws, size_t ws_size,
                              hipStream_t stream) {
    const float* pos = (const float*)d_in[0];
    const float* col = (const float*)d_in[1];
    const float* opa = (const float*)d_in[2];
    const float* scl = (const float*)d_in[3];
    const float* qv  = (const float*)d_in[4];
    const float* tv  = (const float*)d_in[5];
    const float* fx  = (const float*)d_in[6];
    const float* fy  = (const float*)d_in[7];
    const float* cx  = (const float*)d_in[8];
    const float* cy  = (const float*)d_in[9];

    int N = in_sizes[0] / 3;
    int B = in_sizes[4] / 4;

    float4* proj   = (float4*)d_ws;
    float*  accbuf = (float*)((char*)d_ws + (size_t)B * N * 2 * sizeof(float4));
    int     accn   = B * HWP * 4;
    int*    wctr   = (int*)(accbuf + accn);     // one int after accbuf
    float*  outp   = (float*)d_out;

    int tot = N * B;
    proj_kernel<<<(tot + 255) / 256, 256, 0, stream>>>(pos, col, opa, scl, qv, tv,
                                                       fx, fy, cx, cy, proj, N, B);

    // zero accbuf + work counter (counter is the accn-th float slot, bits 0 == int 0)
    zero_kernel<<<(accn + 1 + 255) / 256, 256, 0, stream>>>(accbuf, accn + 1);

    int nchunks = N / CHUNK_G;                  // 256
    int nitems  = B * 8 * nchunks;              // 4096
    accum_kernel<<<NBLOCKS, 256, 0, stream>>>(proj, accbuf, wctr, N, nitems);

    float epsadd = (float)(N / 2048) * 1e-8f;   // reference adds EPS once per 2048-chunk
    final_kernel<<<(B * HWP + 255) / 256, 256, 0, stream>>>(accbuf, outp, B, epsadd);
}

// Round 9
// 340.314 us; speedup vs baseline: 1.7262x; 1.7262x over previous
//
#include <hip/hip_runtime.h>
#include <math.h>

// DifferentiableRenderer: B=2 cameras, N=65536 gaussians, 128x128 image.
// R8 (resubmit; prior attempt hit GPUAcquisitionTimeout, never ran):
// back to static grid (R7 work-stealing failed: counter contention +
// 2x atomics at 2 items/block). One structural change vs R4:
//   TILE_ROWS 16->8, PPT 8->4  =>  4096 blocks = 2 residency waves
//   (freed CU slots backfill; center-out tile rank so heavy tiles first)
//   + ~18% less pair work from the tighter y-band cull.
// Atomic volume invariant (propto GSPLIT * pixels). No unroll-2 (R6 suspect).

#define HH 128
#define WW 128
#define HWP (HH * WW)
#define TILE_ROWS 8
#define NTILES (HH / TILE_ROWS)     // 16
#define PPT 4            // pixels per thread (one column, stride 2 rows)
#define GSPLIT 128       // gaussian splits per tile
#define CHUNK_G 256      // gaussians culled/compacted per chunk

__global__ void proj_kernel(const float* __restrict__ pos,
                            const float* __restrict__ col,
                            const float* __restrict__ opa,
                            const float* __restrict__ scl,
                            const float* __restrict__ qv,
                            const float* __restrict__ tv,
                            const float* fxp, const float* fyp,
                            const float* cxp, const float* cyp,
                            float4* __restrict__ out, int N, int B) {
    int i = blockIdx.x * blockDim.x + threadIdx.x;
    if (i >= N * B) return;
    int b = i / N;
    int g = i - b * N;

    float qw = qv[b * 4 + 0], qx = qv[b * 4 + 1], qy = qv[b * 4 + 2], qz = qv[b * 4 + 3];
    float qn = rsqrtf(qw * qw + qx * qx + qy * qy + qz * qz);
    qw *= qn; qx *= qn; qy *= qn; qz *= qn;
    float r00 = 1.0f - 2.0f * (qy * qy + qz * qz);
    float r01 = 2.0f * (qx * qy - qz * qw);
    float r02 = 2.0f * (qx * qz + qy * qw);
    float r10 = 2.0f * (qx * qy + qz * qw);
    float r11 = 1.0f - 2.0f * (qx * qx + qz * qz);
    float r12 = 2.0f * (qy * qz - qx * qw);
    float r20 = 2.0f * (qx * qz - qy * qw);
    float r21 = 2.0f * (qy * qz + qx * qw);
    float r22 = 1.0f - 2.0f * (qx * qx + qy * qy);

    float X = pos[g * 3 + 0], Y = pos[g * 3 + 1], Z = pos[g * 3 + 2];
    float pcx = r00 * X + r01 * Y + r02 * Z + tv[b * 3 + 0];
    float pcy = r10 * X + r11 * Y + r12 * Z + tv[b * 3 + 1];
    float pcz = r20 * X + r21 * Y + r22 * Z + tv[b * 3 + 2];

    float px = pcx / pcz * (*fxp) + (*cxp);
    float py = pcy / pcz * (*fyp) + (*cyp);

    float sc = scl[g];
    float var = sc * sc;
    float l = __builtin_amdgcn_logf(opa[g]);        // log2(opacity)
    // w = op*exp(-0.5*d2/var) = exp2(l - (s*dx)^2 - (s*dy)^2), s = sqrt(0.5*log2e)/scale
    float s = 0.84932180028801905f / sc;
    // cull radius: keep terms with w >= 2^-45  (d2 <= (45+l)*var*2ln2)
    float d2max = fmaxf(45.0f + l, 0.0f) * var * 1.38629436111989061f;
    float rad = sqrtf(d2max);

    out[(size_t)(b * N + g) * 2 + 0] = make_float4(px, py, s, rad);
    out[(size_t)(b * N + g) * 2 + 1] = make_float4(col[g * 3 + 0], col[g * 3 + 1], col[g * 3 + 2], l);
}

__global__ void zero_kernel(float* __restrict__ p, int n) {
    int i = blockIdx.x * blockDim.x + threadIdx.x;
    if (i < n) p[i] = 0.0f;
}

__global__ __launch_bounds__(256) void accum_kernel(const float4* __restrict__ gdata,
                                                    float* __restrict__ accbuf,
                                                    int N, int gpb) {
    __shared__ float4 shc[CHUNK_G * 2];   // compacted: (px,py,s,l),(r,g,b,2s)
    __shared__ int wcnt[4];
    int gs   = blockIdx.x;          // gaussian split  (fastest -> XCD balance)
    int b    = blockIdx.y;          // camera
    // center-out tile rank: both cameras' heavy tiles dispatch first
    // rank -> tile: {7,8,6,9,5,10,4,11,3,12,2,13,1,14,0,15}
    int tile = (int)((0xF0E1D2C3B4A59687ull >> (blockIdx.z * 4)) & 0xFull);
    int tid  = threadIdx.x;
    int x    = tid & 127;
    int yrow = tid >> 7;            // 0 or 1
    int ytop = tile * TILE_ROWS;
    int wid  = tid >> 6;
    int lane = tid & 63;

    float xf  = (float)x;
    float ylo = (float)ytop;
    float yhi = (float)(ytop + TILE_ROWS - 1);
    float y0f = (float)(ytop + yrow);

    float nr[PPT], ng[PPT], nb[PPT], nd[PPT];
#pragma unroll
    for (int p = 0; p < PPT; ++p) { nr[p] = 0.0f; ng[p] = 0.0f; nb[p] = 0.0f; nd[p] = 0.0f; }

    const float4* gbase = gdata + (size_t)b * N * 2;
    int g0 = gs * gpb;

    for (int cb = 0; cb < gpb; cb += CHUNK_G) {
        // ---- thread-parallel cull: one gaussian per thread (coalesced 32B) ----
        int src = (g0 + cb + tid) * 2;
        float4 f0 = gbase[src];        // px, py, s, rad
        float4 f1 = gbase[src + 1];    // r, g, b, l
        float px = f0.x, py = f0.y, rad = f0.w;
        bool keep = (py + rad >= ylo) & (py - rad <= yhi) &
                    (px + rad >= 0.0f) & (px - rad <= 127.0f);
        unsigned long long m = __ballot(keep);

        __syncthreads();                       // prior dense loop done with shc/wcnt
        if (lane == 0) wcnt[wid] = __popcll(m);
        __syncthreads();                       // wcnt visible
        int base = 0;
        if (wid > 0) base += wcnt[0];
        if (wid > 1) base += wcnt[1];
        if (wid > 2) base += wcnt[2];
        int total = wcnt[0] + wcnt[1] + wcnt[2] + wcnt[3];
        int pos = base + __popcll(m & ((1ull << lane) - 1ull));
        if (keep) {
            shc[pos * 2]     = make_float4(f0.x, f0.y, f0.z, f1.w);        // px,py,s,l
            shc[pos * 2 + 1] = make_float4(f1.x, f1.y, f1.z, f0.z + f0.z); // r,g,b,2s
        }
        __syncthreads();                       // shc visible

        // ---- branch-free dense loop over survivors (broadcast LDS reads) ----
        for (int j = 0; j < total; ++j) {
            float4 a0 = shc[j * 2];
            float4 a1 = shc[j * 2 + 1];
            float s   = a0.z;
            float dx  = a0.x - xf;
            float sdx = s * dx;
            float lm  = __builtin_fmaf(-sdx, sdx, a0.w);   // l - sdx^2
            float sdy = s * (a0.y - y0f);
            float s2  = a1.w;                              // 2s
#pragma unroll
            for (int p = 0; p < PPT; ++p) {
                float e = __builtin_fmaf(-sdy, sdy, lm);
                float w = __builtin_amdgcn_exp2f(e);
                nr[p] = __builtin_fmaf(w, a1.x, nr[p]);
                ng[p] = __builtin_fmaf(w, a1.y, ng[p]);
                nb[p] = __builtin_fmaf(w, a1.z, nb[p]);
                nd[p] += w;
                sdy -= s2;
            }
        }
    }

    float* ab = accbuf + (size_t)b * HWP * 4;
#pragma unroll
    for (int p = 0; p < PPT; ++p) {
        int y = ytop + yrow + p * 2;
        int pix = y * WW + x;
        atomicAdd(ab + pix * 4 + 0, nr[p]);
        atomicAdd(ab + pix * 4 + 1, ng[p]);
        atomicAdd(ab + pix * 4 + 2, nb[p]);
        atomicAdd(ab + pix * 4 + 3, nd[p]);
    }
}

__global__ void final_kernel(const float* __restrict__ accbuf,
                             float* __restrict__ out, int B, float epsadd) {
    int i = blockIdx.x * blockDim.x + threadIdx.x;   // over B*HW
    if (i >= B * HWP) return;
    int b = i / HWP;
    int p = i - b * HWP;
    const float* a = accbuf + (size_t)i * 4;
    float den = fmaxf(a[3] + epsadd, 1e-8f);
    out[(size_t)(b * 3 + 0) * HWP + p] = a[0] / den;
    out[(size_t)(b * 3 + 1) * HWP + p] = a[1] / den;
    out[(size_t)(b * 3 + 2) * HWP + p] = a[2] / den;
}

extern "C" void kernel_launch(void* const* d_in, const int* in_sizes, int n_in,
                              void* d_out, int out_size, void* d_ws, size_t ws_size,
                              hipStream_t stream) {
    const float* pos = (const float*)d_in[0];
    const float* col = (const float*)d_in[1];
    const float* opa = (const float*)d_in[2];
    const float* scl = (const float*)d_in[3];
    const float* qv  = (const float*)d_in[4];
    const float* tv  = (const float*)d_in[5];
    const float* fx  = (const float*)d_in[6];
    const float* fy  = (const float*)d_in[7];
    const float* cx  = (const float*)d_in[8];
    const float* cy  = (const float*)d_in[9];

    int N = in_sizes[0] / 3;
    int B = in_sizes[4] / 4;

    float4* proj   = (float4*)d_ws;
    float*  accbuf = (float*)((char*)d_ws + (size_t)B * N * 2 * sizeof(float4));
    float*  outp   = (float*)d_out;

    int tot = N * B;
    proj_kernel<<<(tot + 255) / 256, 256, 0, stream>>>(pos, col, opa, scl, qv, tv,
                                                       fx, fy, cx, cy, proj, N, B);

    int accn = B * HWP * 4;
    zero_kernel<<<(accn + 255) / 256, 256, 0, stream>>>(accbuf, accn);

    int gpb = N / GSPLIT;   // 512 gaussians per block (2 chunks)
    dim3 grid(GSPLIT, B, NTILES);   // x = gs (XCD balance); z = tile rank (heavy first)
    accum_kernel<<<grid, 256, 0, stream>>>(proj, accbuf, N, gpb);

    float epsadd = (float)(N / 2048) * 1e-8f;  // reference adds EPS once per 2048-chunk
    final_kernel<<<(B * HWP + 255) / 256, 256, 0, stream>>>(accbuf, outp, B, epsadd);
}

// Round 10
// 213.752 us; speedup vs baseline: 2.7483x; 1.5921x over previous
//
#include <hip/hip_runtime.h>
#include <math.h>

// DifferentiableRenderer: B=2 cameras, N=65536 gaussians, 128x128 image.
// R10: the R4..R9 counter series shows duration == WRITE_SIZE / ~1 TB/s in
// every round (R7: 2x atomics -> exactly 2x time). Bottleneck is atomic
// write-through, not scheduling. Single change vs R9: GSPLIT 128->32
// => atomic volume 268 MB -> 67 MB (drain ~67us < ~110us compute floor).
// Grid 32x2x16 = 1024 blocks (4/CU), center-out tile rank kept.

#define HH 128
#define WW 128
#define HWP (HH * WW)
#define TILE_ROWS 8
#define NTILES (HH / TILE_ROWS)     // 16
#define PPT 4            // pixels per thread (one column, stride 2 rows)
#define GSPLIT 32        // gaussian splits per tile (atomic volume ~ GSPLIT)
#define CHUNK_G 256      // gaussians culled/compacted per chunk

__global__ void proj_kernel(const float* __restrict__ pos,
                            const float* __restrict__ col,
                            const float* __restrict__ opa,
                            const float* __restrict__ scl,
                            const float* __restrict__ qv,
                            const float* __restrict__ tv,
                            const float* fxp, const float* fyp,
                            const float* cxp, const float* cyp,
                            float4* __restrict__ out, int N, int B) {
    int i = blockIdx.x * blockDim.x + threadIdx.x;
    if (i >= N * B) return;
    int b = i / N;
    int g = i - b * N;

    float qw = qv[b * 4 + 0], qx = qv[b * 4 + 1], qy = qv[b * 4 + 2], qz = qv[b * 4 + 3];
    float qn = rsqrtf(qw * qw + qx * qx + qy * qy + qz * qz);
    qw *= qn; qx *= qn; qy *= qn; qz *= qn;
    float r00 = 1.0f - 2.0f * (qy * qy + qz * qz);
    float r01 = 2.0f * (qx * qy - qz * qw);
    float r02 = 2.0f * (qx * qz + qy * qw);
    float r10 = 2.0f * (qx * qy + qz * qw);
    float r11 = 1.0f - 2.0f * (qx * qx + qz * qz);
    float r12 = 2.0f * (qy * qz - qx * qw);
    float r20 = 2.0f * (qx * qz - qy * qw);
    float r21 = 2.0f * (qy * qz + qx * qw);
    float r22 = 1.0f - 2.0f * (qx * qx + qy * qy);

    float X = pos[g * 3 + 0], Y = pos[g * 3 + 1], Z = pos[g * 3 + 2];
    float pcx = r00 * X + r01 * Y + r02 * Z + tv[b * 3 + 0];
    float pcy = r10 * X + r11 * Y + r12 * Z + tv[b * 3 + 1];
    float pcz = r20 * X + r21 * Y + r22 * Z + tv[b * 3 + 2];

    float px = pcx / pcz * (*fxp) + (*cxp);
    float py = pcy / pcz * (*fyp) + (*cyp);

    float sc = scl[g];
    float var = sc * sc;
    float l = __builtin_amdgcn_logf(opa[g]);        // log2(opacity)
    // w = op*exp(-0.5*d2/var) = exp2(l - (s*dx)^2 - (s*dy)^2), s = sqrt(0.5*log2e)/scale
    float s = 0.84932180028801905f / sc;
    // cull radius: keep terms with w >= 2^-45  (d2 <= (45+l)*var*2ln2)
    float d2max = fmaxf(45.0f + l, 0.0f) * var * 1.38629436111989061f;
    float rad = sqrtf(d2max);

    out[(size_t)(b * N + g) * 2 + 0] = make_float4(px, py, s, rad);
    out[(size_t)(b * N + g) * 2 + 1] = make_float4(col[g * 3 + 0], col[g * 3 + 1], col[g * 3 + 2], l);
}

__global__ void zero_kernel(float* __restrict__ p, int n) {
    int i = blockIdx.x * blockDim.x + threadIdx.x;
    if (i < n) p[i] = 0.0f;
}

__global__ __launch_bounds__(256) void accum_kernel(const float4* __restrict__ gdata,
                                                    float* __restrict__ accbuf,
                                                    int N, int gpb) {
    __shared__ float4 shc[CHUNK_G * 2];   // compacted: (px,py,s,l),(r,g,b,2s)
    __shared__ int wcnt[4];
    int gs   = blockIdx.x;          // gaussian split  (fastest -> XCD balance)
    int b    = blockIdx.y;          // camera
    // center-out tile rank: both cameras' heavy tiles dispatch first
    // rank -> tile: {7,8,6,9,5,10,4,11,3,12,2,13,1,14,0,15}
    int tile = (int)((0xF0E1D2C3B4A59687ull >> (blockIdx.z * 4)) & 0xFull);
    int tid  = threadIdx.x;
    int x    = tid & 127;
    int yrow = tid >> 7;            // 0 or 1
    int ytop = tile * TILE_ROWS;
    int wid  = tid >> 6;
    int lane = tid & 63;

    float xf  = (float)x;
    float ylo = (float)ytop;
    float yhi = (float)(ytop + TILE_ROWS - 1);
    float y0f = (float)(ytop + yrow);

    float nr[PPT], ng[PPT], nb[PPT], nd[PPT];
#pragma unroll
    for (int p = 0; p < PPT; ++p) { nr[p] = 0.0f; ng[p] = 0.0f; nb[p] = 0.0f; nd[p] = 0.0f; }

    const float4* gbase = gdata + (size_t)b * N * 2;
    int g0 = gs * gpb;

    for (int cb = 0; cb < gpb; cb += CHUNK_G) {
        // ---- thread-parallel cull: one gaussian per thread (coalesced 32B) ----
        int src = (g0 + cb + tid) * 2;
        float4 f0 = gbase[src];        // px, py, s, rad
        float4 f1 = gbase[src + 1];    // r, g, b, l
        float px = f0.x, py = f0.y, rad = f0.w;
        bool keep = (py + rad >= ylo) & (py - rad <= yhi) &
                    (px + rad >= 0.0f) & (px - rad <= 127.0f);
        unsigned long long m = __ballot(keep);

        __syncthreads();                       // prior dense loop done with shc/wcnt
        if (lane == 0) wcnt[wid] = __popcll(m);
        __syncthreads();                       // wcnt visible
        int base = 0;
        if (wid > 0) base += wcnt[0];
        if (wid > 1) base += wcnt[1];
        if (wid > 2) base += wcnt[2];
        int total = wcnt[0] + wcnt[1] + wcnt[2] + wcnt[3];
        int pos = base + __popcll(m & ((1ull << lane) - 1ull));
        if (keep) {
            shc[pos * 2]     = make_float4(f0.x, f0.y, f0.z, f1.w);        // px,py,s,l
            shc[pos * 2 + 1] = make_float4(f1.x, f1.y, f1.z, f0.z + f0.z); // r,g,b,2s
        }
        __syncthreads();                       // shc visible

        // ---- branch-free dense loop over survivors (broadcast LDS reads) ----
        for (int j = 0; j < total; ++j) {
            float4 a0 = shc[j * 2];
            float4 a1 = shc[j * 2 + 1];
            float s   = a0.z;
            float dx  = a0.x - xf;
            float sdx = s * dx;
            float lm  = __builtin_fmaf(-sdx, sdx, a0.w);   // l - sdx^2
            float sdy = s * (a0.y - y0f);
            float s2  = a1.w;                              // 2s
#pragma unroll
            for (int p = 0; p < PPT; ++p) {
                float e = __builtin_fmaf(-sdy, sdy, lm);
                float w = __builtin_amdgcn_exp2f(e);
                nr[p] = __builtin_fmaf(w, a1.x, nr[p]);
                ng[p] = __builtin_fmaf(w, a1.y, ng[p]);
                nb[p] = __builtin_fmaf(w, a1.z, nb[p]);
                nd[p] += w;
                sdy -= s2;
            }
        }
    }

    float* ab = accbuf + (size_t)b * HWP * 4;
#pragma unroll
    for (int p = 0; p < PPT; ++p) {
        int y = ytop + yrow + p * 2;
        int pix = y * WW + x;
        atomicAdd(ab + pix * 4 + 0, nr[p]);
        atomicAdd(ab + pix * 4 + 1, ng[p]);
        atomicAdd(ab + pix * 4 + 2, nb[p]);
        atomicAdd(ab + pix * 4 + 3, nd[p]);
    }
}

__global__ void final_kernel(const float* __restrict__ accbuf,
                             float* __restrict__ out, int B, float epsadd) {
    int i = blockIdx.x * blockDim.x + threadIdx.x;   // over B*HW
    if (i >= B * HWP) return;
    int b = i / HWP;
    int p = i - b * HWP;
    const float* a = accbuf + (size_t)i * 4;
    float den = fmaxf(a[3] + epsadd, 1e-8f);
    out[(size_t)(b * 3 + 0) * HWP + p] = a[0] / den;
    out[(size_t)(b * 3 + 1) * HWP + p] = a[1] / den;
    out[(size_t)(b * 3 + 2) * HWP + p] = a[2] / den;
}

extern "C" void kernel_launch(void* const* d_in, const int* in_sizes, int n_in,
                              void* d_out, int out_size, void* d_ws, size_t ws_size,
                              hipStream_t stream) {
    const float* pos = (const float*)d_in[0];
    const float* col = (const float*)d_in[1];
    const float* opa = (const float*)d_in[2];
    const float* scl = (const float*)d_in[3];
    const float* qv  = (const float*)d_in[4];
    const float* tv  = (const float*)d_in[5];
    const float* fx  = (const float*)d_in[6];
    const float* fy  = (const float*)d_in[7];
    const float* cx  = (const float*)d_in[8];
    const float* cy  = (const float*)d_in[9];

    int N = in_sizes[0] / 3;
    int B = in_sizes[4] / 4;

    float4* proj   = (float4*)d_ws;
    float*  accbuf = (float*)((char*)d_ws + (size_t)B * N * 2 * sizeof(float4));
    float*  outp   = (float*)d_out;

    int tot = N * B;
    proj_kernel<<<(tot + 255) / 256, 256, 0, stream>>>(pos, col, opa, scl, qv, tv,
                                                       fx, fy, cx, cy, proj, N, B);

    int accn = B * HWP * 4;
    zero_kernel<<<(accn + 255) / 256, 256, 0, stream>>>(accbuf, accn);

    int gpb = N / GSPLIT;   // 2048 gaussians per block (8 chunks)
    dim3 grid(GSPLIT, B, NTILES);   // x = gs (XCD balance); z = tile rank (heavy first)
    accum_kernel<<<grid, 256, 0, stream>>>(proj, accbuf, N, gpb);

    float epsadd = (float)(N / 2048) * 1e-8f;  // reference adds EPS once per 2048-chunk
    final_kernel<<<(B * HWP + 255) / 256, 256, 0, stream>>>(accbuf, outp, B, epsadd);
}

// Round 11
// 205.769 us; speedup vs baseline: 2.8549x; 1.0388x over previous
//
#include <hip/hip_runtime.h>
#include <math.h>

// DifferentiableRenderer: B=2 cameras, N=65536 gaussians, 128x128 image.
// R11: R10 confirmed the atomic write-through roofline (dur == WRITE/1TB/s).
// Change the write path: per-split partials via plain coalesced float4
// stores (16.8 MB, L2 writeback) + 32-way reduce fused into final_kernel.
// zero_kernel deleted (stores need no init). Accum structure = R10.

#define HH 128
#define WW 128
#define HWP (HH * WW)
#define TILE_ROWS 8
#define NTILES (HH / TILE_ROWS)     // 16
#define PPT 4            // pixels per thread (one column, stride 2 rows)
#define GSPLIT 32        // gaussian splits per tile (partials per pixel)
#define CHUNK_G 256      // gaussians culled/compacted per chunk

__global__ void proj_kernel(const float* __restrict__ pos,
                            const float* __restrict__ col,
                            const float* __restrict__ opa,
                            const float* __restrict__ scl,
                            const float* __restrict__ qv,
                            const float* __restrict__ tv,
                            const float* fxp, const float* fyp,
                            const float* cxp, const float* cyp,
                            float4* __restrict__ out, int N, int B) {
    int i = blockIdx.x * blockDim.x + threadIdx.x;
    if (i >= N * B) return;
    int b = i / N;
    int g = i - b * N;

    float qw = qv[b * 4 + 0], qx = qv[b * 4 + 1], qy = qv[b * 4 + 2], qz = qv[b * 4 + 3];
    float qn = rsqrtf(qw * qw + qx * qx + qy * qy + qz * qz);
    qw *= qn; qx *= qn; qy *= qn; qz *= qn;
    float r00 = 1.0f - 2.0f * (qy * qy + qz * qz);
    float r01 = 2.0f * (qx * qy - qz * qw);
    float r02 = 2.0f * (qx * qz + qy * qw);
    float r10 = 2.0f * (qx * qy + qz * qw);
    float r11 = 1.0f - 2.0f * (qx * qx + qz * qz);
    float r12 = 2.0f * (qy * qz - qx * qw);
    float r20 = 2.0f * (qx * qz - qy * qw);
    float r21 = 2.0f * (qy * qz + qx * qw);
    float r22 = 1.0f - 2.0f * (qx * qx + qy * qy);

    float X = pos[g * 3 + 0], Y = pos[g * 3 + 1], Z = pos[g * 3 + 2];
    float pcx = r00 * X + r01 * Y + r02 * Z + tv[b * 3 + 0];
    float pcy = r10 * X + r11 * Y + r12 * Z + tv[b * 3 + 1];
    float pcz = r20 * X + r21 * Y + r22 * Z + tv[b * 3 + 2];

    float px = pcx / pcz * (*fxp) + (*cxp);
    float py = pcy / pcz * (*fyp) + (*cyp);

    float sc = scl[g];
    float var = sc * sc;
    float l = __builtin_amdgcn_logf(opa[g]);        // log2(opacity)
    // w = op*exp(-0.5*d2/var) = exp2(l - (s*dx)^2 - (s*dy)^2), s = sqrt(0.5*log2e)/scale
    float s = 0.84932180028801905f / sc;
    // cull radius: keep terms with w >= 2^-45  (d2 <= (45+l)*var*2ln2)
    float d2max = fmaxf(45.0f + l, 0.0f) * var * 1.38629436111989061f;
    float rad = sqrtf(d2max);

    out[(size_t)(b * N + g) * 2 + 0] = make_float4(px, py, s, rad);
    out[(size_t)(b * N + g) * 2 + 1] = make_float4(col[g * 3 + 0], col[g * 3 + 1], col[g * 3 + 2], l);
}

__global__ __launch_bounds__(256) void accum_kernel(const float4* __restrict__ gdata,
                                                    float4* __restrict__ partial,
                                                    int N, int gpb) {
    __shared__ float4 shc[CHUNK_G * 2];   // compacted: (px,py,s,l),(r,g,b,2s)
    __shared__ int wcnt[4];
    int gs   = blockIdx.x;          // gaussian split  (fastest -> XCD balance)
    int b    = blockIdx.y;          // camera
    // center-out tile rank: both cameras' heavy tiles dispatch first
    // rank -> tile: {7,8,6,9,5,10,4,11,3,12,2,13,1,14,0,15}
    int tile = (int)((0xF0E1D2C3B4A59687ull >> (blockIdx.z * 4)) & 0xFull);
    int tid  = threadIdx.x;
    int x    = tid & 127;
    int yrow = tid >> 7;            // 0 or 1
    int ytop = tile * TILE_ROWS;
    int wid  = tid >> 6;
    int lane = tid & 63;

    float xf  = (float)x;
    float ylo = (float)ytop;
    float yhi = (float)(ytop + TILE_ROWS - 1);
    float y0f = (float)(ytop + yrow);

    float nr[PPT], ng[PPT], nb[PPT], nd[PPT];
#pragma unroll
    for (int p = 0; p < PPT; ++p) { nr[p] = 0.0f; ng[p] = 0.0f; nb[p] = 0.0f; nd[p] = 0.0f; }

    const float4* gbase = gdata + (size_t)b * N * 2;
    int g0 = gs * gpb;

    for (int cb = 0; cb < gpb; cb += CHUNK_G) {
        // ---- thread-parallel cull: one gaussian per thread (coalesced 32B) ----
        int src = (g0 + cb + tid) * 2;
        float4 f0 = gbase[src];        // px, py, s, rad
        float4 f1 = gbase[src + 1];    // r, g, b, l
        float px = f0.x, py = f0.y, rad = f0.w;
        bool keep = (py + rad >= ylo) & (py - rad <= yhi) &
                    (px + rad >= 0.0f) & (px - rad <= 127.0f);
        unsigned long long m = __ballot(keep);

        __syncthreads();                       // prior dense loop done with shc/wcnt
        if (lane == 0) wcnt[wid] = __popcll(m);
        __syncthreads();                       // wcnt visible
        int base = 0;
        if (wid > 0) base += wcnt[0];
        if (wid > 1) base += wcnt[1];
        if (wid > 2) base += wcnt[2];
        int total = wcnt[0] + wcnt[1] + wcnt[2] + wcnt[3];
        int pos = base + __popcll(m & ((1ull << lane) - 1ull));
        if (keep) {
            shc[pos * 2]     = make_float4(f0.x, f0.y, f0.z, f1.w);        // px,py,s,l
            shc[pos * 2 + 1] = make_float4(f1.x, f1.y, f1.z, f0.z + f0.z); // r,g,b,2s
        }
        __syncthreads();                       // shc visible

        // ---- branch-free dense loop over survivors (broadcast LDS reads) ----
        for (int j = 0; j < total; ++j) {
            float4 a0 = shc[j * 2];
            float4 a1 = shc[j * 2 + 1];
            float s   = a0.z;
            float dx  = a0.x - xf;
            float sdx = s * dx;
            float lm  = __builtin_fmaf(-sdx, sdx, a0.w);   // l - sdx^2
            float sdy = s * (a0.y - y0f);
            float s2  = a1.w;                              // 2s
#pragma unroll
            for (int p = 0; p < PPT; ++p) {
                float e = __builtin_fmaf(-sdy, sdy, lm);
                float w = __builtin_amdgcn_exp2f(e);
                nr[p] = __builtin_fmaf(w, a1.x, nr[p]);
                ng[p] = __builtin_fmaf(w, a1.y, ng[p]);
                nb[p] = __builtin_fmaf(w, a1.z, nb[p]);
                nd[p] += w;
                sdy -= s2;
            }
        }
    }

    // ---- plain coalesced partial store (no atomics, no init needed) ----
    float4* pb = partial + ((size_t)gs * 2 + b) * HWP;   // [gs][b][pix]
#pragma unroll
    for (int p = 0; p < PPT; ++p) {
        int y = ytop + yrow + p * 2;
        int pix = y * WW + x;
        pb[pix] = make_float4(nr[p], ng[p], nb[p], nd[p]);
    }
}

__global__ void final_kernel(const float4* __restrict__ partial,
                             float* __restrict__ out, int B, float epsadd) {
    int i = blockIdx.x * blockDim.x + threadIdx.x;   // over B*HW
    if (i >= B * HWP) return;
    int b = i / HWP;
    int p = i - b * HWP;
    float sr = 0.0f, sg = 0.0f, sb = 0.0f, sd = 0.0f;
#pragma unroll 8
    for (int gs = 0; gs < GSPLIT; ++gs) {
        float4 v = partial[((size_t)gs * 2 + b) * HWP + p];
        sr += v.x; sg += v.y; sb += v.z; sd += v.w;
    }
    float den = fmaxf(sd + epsadd, 1e-8f);
    out[(size_t)(b * 3 + 0) * HWP + p] = sr / den;
    out[(size_t)(b * 3 + 1) * HWP + p] = sg / den;
    out[(size_t)(b * 3 + 2) * HWP + p] = sb / den;
}

extern "C" void kernel_launch(void* const* d_in, const int* in_sizes, int n_in,
                              void* d_out, int out_size, void* d_ws, size_t ws_size,
                              hipStream_t stream) {
    const float* pos = (const float*)d_in[0];
    const float* col = (const float*)d_in[1];
    const float* opa = (const float*)d_in[2];
    const float* scl = (const float*)d_in[3];
    const float* qv  = (const float*)d_in[4];
    const float* tv  = (const float*)d_in[5];
    const float* fx  = (const float*)d_in[6];
    const float* fy  = (const float*)d_in[7];
    const float* cx  = (const float*)d_in[8];
    const float* cy  = (const float*)d_in[9];

    int N = in_sizes[0] / 3;
    int B = in_sizes[4] / 4;

    float4* proj    = (float4*)d_ws;
    float4* partial = (float4*)((char*)d_ws + (size_t)B * N * 2 * sizeof(float4));
    float*  outp    = (float*)d_out;

    int tot = N * B;
    proj_kernel<<<(tot + 255) / 256, 256, 0, stream>>>(pos, col, opa, scl, qv, tv,
                                                       fx, fy, cx, cy, proj, N, B);

    int gpb = N / GSPLIT;   // 2048 gaussians per block (8 chunks)
    dim3 grid(GSPLIT, B, NTILES);   // x = gs (XCD balance); z = tile rank (heavy first)
    accum_kernel<<<grid, 256, 0, stream>>>(proj, partial, N, gpb);

    float epsadd = (float)(N / 2048) * 1e-8f;  // reference adds EPS once per 2048-chunk
    final_kernel<<<(B * HWP + 255) / 256, 256, 0, stream>>>(partial, outp, B, epsadd);
}

// Round 14
// 189.950 us; speedup vs baseline: 3.0927x; 1.0833x over previous
//
#include <hip/hip_runtime.h>
#include <math.h>

// DifferentiableRenderer: B=2 cameras, N=65536 gaussians, 128x128 image.
// R12 (2nd resubmit; two consecutive GPUAcquisitionTimeouts, never ran):
// x-tiling. R11 is VALU-issue bound (busy ~108us); packed fp32 is NOT
// a lever on CDNA4 (157.3 TF == scalar issue rate). Cut pair-iterations:
// tiles 128x8 -> 64x16 (2 x-halves x 8 y-bands, 64x*4y threads, PPT=4,
// y-stride 4). Cull window (16+2r)(64+2r) vs (8+2r)(128+2r) ~= 0.72x work.
// Partials are pixel-indexed so WRITE_SIZE is invariant under spatial tiling.

#define HH 128
#define WW 128
#define HWP (HH * WW)
#define TILE_ROWS 16
#define TILE_COLS 64
#define NXT 2            // x-tiles
#define NYB 8            // y-bands
#define PPT 4            // pixels per thread (one column, stride 4 rows)
#define GSPLIT 32        // gaussian splits (partials per pixel)
#define CHUNK_G 256      // gaussians culled/compacted per chunk

__global__ void proj_kernel(const float* __restrict__ pos,
                            const float* __restrict__ col,
                            const float* __restrict__ opa,
                            const float* __restrict__ scl,
                            const float* __restrict__ qv,
                            const float* __restrict__ tv,
                            const float* fxp, const float* fyp,
                            const float* cxp, const float* cyp,
                            float4* __restrict__ out, int N, int B) {
    int i = blockIdx.x * blockDim.x + threadIdx.x;
    if (i >= N * B) return;
    int b = i / N;
    int g = i - b * N;

    float qw = qv[b * 4 + 0], qx = qv[b * 4 + 1], qy = qv[b * 4 + 2], qz = qv[b * 4 + 3];
    float qn = rsqrtf(qw * qw + qx * qx + qy * qy + qz * qz);
    qw *= qn; qx *= qn; qy *= qn; qz *= qn;
    float r00 = 1.0f - 2.0f * (qy * qy + qz * qz);
    float r01 = 2.0f * (qx * qy - qz * qw);
    float r02 = 2.0f * (qx * qz + qy * qw);
    float r10 = 2.0f * (qx * qy + qz * qw);
    float r11 = 1.0f - 2.0f * (qx * qx + qz * qz);
    float r12 = 2.0f * (qy * qz - qx * qw);
    float r20 = 2.0f * (qx * qz - qy * qw);
    float r21 = 2.0f * (qy * qz + qx * qw);
    float r22 = 1.0f - 2.0f * (qx * qx + qy * qy);

    float X = pos[g * 3 + 0], Y = pos[g * 3 + 1], Z = pos[g * 3 + 2];
    float pcx = r00 * X + r01 * Y + r02 * Z + tv[b * 3 + 0];
    float pcy = r10 * X + r11 * Y + r12 * Z + tv[b * 3 + 1];
    float pcz = r20 * X + r21 * Y + r22 * Z + tv[b * 3 + 2];

    float px = pcx / pcz * (*fxp) + (*cxp);
    float py = pcy / pcz * (*fyp) + (*cyp);

    float sc = scl[g];
    float var = sc * sc;
    float l = __builtin_amdgcn_logf(opa[g]);        // log2(opacity)
    // w = op*exp(-0.5*d2/var) = exp2(l - (s*dx)^2 - (s*dy)^2), s = sqrt(0.5*log2e)/scale
    float s = 0.84932180028801905f / sc;
    // cull radius: keep terms with w >= 2^-45  (d2 <= (45+l)*var*2ln2)
    float d2max = fmaxf(45.0f + l, 0.0f) * var * 1.38629436111989061f;
    float rad = sqrtf(d2max);

    out[(size_t)(b * N + g) * 2 + 0] = make_float4(px, py, s, rad);
    out[(size_t)(b * N + g) * 2 + 1] = make_float4(col[g * 3 + 0], col[g * 3 + 1], col[g * 3 + 2], l);
}

__global__ __launch_bounds__(256) void accum_kernel(const float4* __restrict__ gdata,
                                                    float4* __restrict__ partial,
                                                    int N, int gpb) {
    __shared__ float4 shc[CHUNK_G * 2];   // compacted: (px,py,s,l),(r,g,b,4s)
    __shared__ int wcnt[4];
    int gs   = blockIdx.x;          // gaussian split  (fastest -> XCD balance)
    int b    = blockIdx.y & 1;      // camera
    int tx   = blockIdx.y >> 1;     // x-half (0,1)
    // center-out y-band rank: heavy bands dispatch first. perm {3,4,2,5,1,6,0,7}
    int yb   = (int)((0x70615243u >> (blockIdx.z * 4)) & 0xFu);
    int tid  = threadIdx.x;
    int xloc = tid & 63;
    int yrow = tid >> 6;            // 0..3 (wave id)
    int ytop = yb * TILE_ROWS;
    int x    = tx * TILE_COLS + xloc;
    int wid  = tid >> 6;
    int lane = tid & 63;

    float xf  = (float)x;
    float xlo = (float)(tx * TILE_COLS);
    float xhi = (float)(tx * TILE_COLS + TILE_COLS - 1);
    float ylo = (float)ytop;
    float yhi = (float)(ytop + TILE_ROWS - 1);
    float y0f = (float)(ytop + yrow);

    float nr[PPT], ng[PPT], nb[PPT], nd[PPT];
#pragma unroll
    for (int p = 0; p < PPT; ++p) { nr[p] = 0.0f; ng[p] = 0.0f; nb[p] = 0.0f; nd[p] = 0.0f; }

    const float4* gbase = gdata + (size_t)b * N * 2;
    int g0 = gs * gpb;

    for (int cb = 0; cb < gpb; cb += CHUNK_G) {
        // ---- thread-parallel cull: one gaussian per thread (coalesced 32B) ----
        int src = (g0 + cb + tid) * 2;
        float4 f0 = gbase[src];        // px, py, s, rad
        float4 f1 = gbase[src + 1];    // r, g, b, l
        float px = f0.x, py = f0.y, rad = f0.w;
        bool keep = (py + rad >= ylo) & (py - rad <= yhi) &
                    (px + rad >= xlo) & (px - rad <= xhi);
        unsigned long long m = __ballot(keep);

        __syncthreads();                       // prior dense loop done with shc/wcnt
        if (lane == 0) wcnt[wid] = __popcll(m);
        __syncthreads();                       // wcnt visible
        int base = 0;
        if (wid > 0) base += wcnt[0];
        if (wid > 1) base += wcnt[1];
        if (wid > 2) base += wcnt[2];
        int total = wcnt[0] + wcnt[1] + wcnt[2] + wcnt[3];
        int pos = base + __popcll(m & ((1ull << lane) - 1ull));
        if (keep) {
            shc[pos * 2]     = make_float4(f0.x, f0.y, f0.z, f1.w);            // px,py,s,l
            shc[pos * 2 + 1] = make_float4(f1.x, f1.y, f1.z, 4.0f * f0.z);     // r,g,b,4s
        }
        __syncthreads();                       // shc visible

        // ---- branch-free dense loop over survivors (broadcast LDS reads) ----
        for (int j = 0; j < total; ++j) {
            float4 a0 = shc[j * 2];
            float4 a1 = shc[j * 2 + 1];
            float s   = a0.z;
            float dx  = a0.x - xf;
            float sdx = s * dx;
            float lm  = __builtin_fmaf(-sdx, sdx, a0.w);   // l - sdx^2
            float sdy = s * (a0.y - y0f);
            float s4  = a1.w;                              // 4s (y-stride 4)
#pragma unroll
            for (int p = 0; p < PPT; ++p) {
                float e = __builtin_fmaf(-sdy, sdy, lm);
                float w = __builtin_amdgcn_exp2f(e);
                nr[p] = __builtin_fmaf(w, a1.x, nr[p]);
                ng[p] = __builtin_fmaf(w, a1.y, ng[p]);
                nb[p] = __builtin_fmaf(w, a1.z, nb[p]);
                nd[p] += w;
                sdy -= s4;
            }
        }
    }

    // ---- plain coalesced partial store (no atomics, no init needed) ----
    float4* pb = partial + ((size_t)gs * 2 + b) * HWP;   // [gs][b][pix]
#pragma unroll
    for (int p = 0; p < PPT; ++p) {
        int y = ytop + yrow + p * 4;
        int pix = y * WW + x;
        pb[pix] = make_float4(nr[p], ng[p], nb[p], nd[p]);
    }
}

__global__ void final_kernel(const float4* __restrict__ partial,
                             float* __restrict__ out, int B, float epsadd) {
    int i = blockIdx.x * blockDim.x + threadIdx.x;   // over B*HW
    if (i >= B * HWP) return;
    int b = i / HWP;
    int p = i - b * HWP;
    float sr = 0.0f, sg = 0.0f, sb = 0.0f, sd = 0.0f;
#pragma unroll 8
    for (int gs = 0; gs < GSPLIT; ++gs) {
        float4 v = partial[((size_t)gs * 2 + b) * HWP + p];
        sr += v.x; sg += v.y; sb += v.z; sd += v.w;
    }
    float den = fmaxf(sd + epsadd, 1e-8f);
    out[(size_t)(b * 3 + 0) * HWP + p] = sr / den;
    out[(size_t)(b * 3 + 1) * HWP + p] = sg / den;
    out[(size_t)(b * 3 + 2) * HWP + p] = sb / den;
}

extern "C" void kernel_launch(void* const* d_in, const int* in_sizes, int n_in,
                              void* d_out, int out_size, void* d_ws, size_t ws_size,
                              hipStream_t stream) {
    const float* pos = (const float*)d_in[0];
    const float* col = (const float*)d_in[1];
    const float* opa = (const float*)d_in[2];
    const float* scl = (const float*)d_in[3];
    const float* qv  = (const float*)d_in[4];
    const float* tv  = (const float*)d_in[5];
    const float* fx  = (const float*)d_in[6];
    const float* fy  = (const float*)d_in[7];
    const float* cx  = (const float*)d_in[8];
    const float* cy  = (const float*)d_in[9];

    int N = in_sizes[0] / 3;
    int B = in_sizes[4] / 4;

    float4* proj    = (float4*)d_ws;
    float4* partial = (float4*)((char*)d_ws + (size_t)B * N * 2 * sizeof(float4));
    float*  outp    = (float*)d_out;

    int tot = N * B;
    proj_kernel<<<(tot + 255) / 256, 256, 0, stream>>>(pos, col, opa, scl, qv, tv,
                                                       fx, fy, cx, cy, proj, N, B);

    int gpb = N / GSPLIT;   // 2048 gaussians per block (8 chunks)
    dim3 grid(GSPLIT, B * NXT, NYB);   // x = gs (XCD balance); z = y-band rank
    accum_kernel<<<grid, 256, 0, stream>>>(proj, partial, N, gpb);

    float epsadd = (float)(N / 2048) * 1e-8f;  // reference adds EPS once per 2048-chunk
    final_kernel<<<(B * HWP + 255) / 256, 256, 0, stream>>>(partial, outp, B, epsadd);
}

// Round 15
// 160.990 us; speedup vs baseline: 3.6490x; 1.1799x over previous
//
#include <hip/hip_runtime.h>
#include <math.h>

// DifferentiableRenderer: B=2 cameras, N=65536 gaussians, 128x128 image.
// R15: calibrated pair-work model (r_eff~25px, work ~ N*(Th+2r)(Tw+2r)):
// tiles 64x16 -> 32x16 (0.82x busy incl. PPT amortization penalty), PPT=2,
// threads 32x*8y. 2048 blocks; grid(32,2,32) with z=(tx,yb-rank) so each CU
// (blocks c+256k) gets all 4 x-tiles and paired y-bands {r,r+4} whose masses
// sum ~const -> per-CU work uniform. Band rank order {3,4,2,5,7,0,6,1}.

#define HH 128
#define WW 128
#define HWP (HH * WW)
#define TILE_ROWS 16
#define TILE_COLS 32
#define NXT 4            // x-tiles
#define NYB 8            // y-bands
#define PPT 2            // pixels per thread (one column, stride 8 rows)
#define GSPLIT 32        // gaussian splits (partials per pixel)
#define CHUNK_G 256      // gaussians culled/compacted per chunk

__global__ void proj_kernel(const float* __restrict__ pos,
                            const float* __restrict__ col,
                            const float* __restrict__ opa,
                            const float* __restrict__ scl,
                            const float* __restrict__ qv,
                            const float* __restrict__ tv,
                            const float* fxp, const float* fyp,
                            const float* cxp, const float* cyp,
                            float4* __restrict__ out, int N, int B) {
    int i = blockIdx.x * blockDim.x + threadIdx.x;
    if (i >= N * B) return;
    int b = i / N;
    int g = i - b * N;

    float qw = qv[b * 4 + 0], qx = qv[b * 4 + 1], qy = qv[b * 4 + 2], qz = qv[b * 4 + 3];
    float qn = rsqrtf(qw * qw + qx * qx + qy * qy + qz * qz);
    qw *= qn; qx *= qn; qy *= qn; qz *= qn;
    float r00 = 1.0f - 2.0f * (qy * qy + qz * qz);
    float r01 = 2.0f * (qx * qy - qz * qw);
    float r02 = 2.0f * (qx * qz + qy * qw);
    float r10 = 2.0f * (qx * qy + qz * qw);
    float r11 = 1.0f - 2.0f * (qx * qx + qz * qz);
    float r12 = 2.0f * (qy * qz - qx * qw);
    float r20 = 2.0f * (qx * qz - qy * qw);
    float r21 = 2.0f * (qy * qz + qx * qw);
    float r22 = 1.0f - 2.0f * (qx * qx + qy * qy);

    float X = pos[g * 3 + 0], Y = pos[g * 3 + 1], Z = pos[g * 3 + 2];
    float pcx = r00 * X + r01 * Y + r02 * Z + tv[b * 3 + 0];
    float pcy = r10 * X + r11 * Y + r12 * Z + tv[b * 3 + 1];
    float pcz = r20 * X + r21 * Y + r22 * Z + tv[b * 3 + 2];

    float px = pcx / pcz * (*fxp) + (*cxp);
    float py = pcy / pcz * (*fyp) + (*cyp);

    float sc = scl[g];
    float var = sc * sc;
    float l = __builtin_amdgcn_logf(opa[g]);        // log2(opacity)
    // w = op*exp(-0.5*d2/var) = exp2(l - (s*dx)^2 - (s*dy)^2), s = sqrt(0.5*log2e)/scale
    float s = 0.84932180028801905f / sc;
    // cull radius: keep terms with w >= 2^-45  (d2 <= (45+l)*var*2ln2)
    float d2max = fmaxf(45.0f + l, 0.0f) * var * 1.38629436111989061f;
    float rad = sqrtf(d2max);

    out[(size_t)(b * N + g) * 2 + 0] = make_float4(px, py, s, rad);
    out[(size_t)(b * N + g) * 2 + 1] = make_float4(col[g * 3 + 0], col[g * 3 + 1], col[g * 3 + 2], l);
}

__global__ __launch_bounds__(256) void accum_kernel(const float4* __restrict__ gdata,
                                                    float4* __restrict__ partial,
                                                    int N, int gpb) {
    __shared__ float4 shc[CHUNK_G * 2];   // compacted: (px,py,s,l),(r,g,b,8s)
    __shared__ int wcnt[4];
    int gs   = blockIdx.x;          // gaussian split  (fastest -> XCD balance)
    int b    = blockIdx.y;          // camera
    int z    = blockIdx.z;          // 0..31 = (tx, yb-rank)
    int tx   = z >> 3;              // x-tile 0..3
    // y-band rank {3,4,2,5,7,0,6,1}: pairs {r,r+4} have ~equal mass sums,
    // so each CU (which receives ranks r and r+4 per x-tile) is load-uniform.
    int yb   = (int)((0x16075243u >> ((z & 7) * 4)) & 0xFu);
    int tid  = threadIdx.x;
    int xloc = tid & 31;
    int yrow = tid >> 5;            // 0..7
    int ytop = yb * TILE_ROWS;
    int x    = tx * TILE_COLS + xloc;
    int wid  = tid >> 6;
    int lane = tid & 63;

    float xf  = (float)x;
    float xlo = (float)(tx * TILE_COLS);
    float xhi = (float)(tx * TILE_COLS + TILE_COLS - 1);
    float ylo = (float)ytop;
    float yhi = (float)(ytop + TILE_ROWS - 1);
    float y0f = (float)(ytop + yrow);

    float nr[PPT], ng[PPT], nb[PPT], nd[PPT];
#pragma unroll
    for (int p = 0; p < PPT; ++p) { nr[p] = 0.0f; ng[p] = 0.0f; nb[p] = 0.0f; nd[p] = 0.0f; }

    const float4* gbase = gdata + (size_t)b * N * 2;
    int g0 = gs * gpb;

    for (int cb = 0; cb < gpb; cb += CHUNK_G) {
        // ---- thread-parallel cull: one gaussian per thread (coalesced 32B) ----
        int src = (g0 + cb + tid) * 2;
        float4 f0 = gbase[src];        // px, py, s, rad
        float4 f1 = gbase[src + 1];    // r, g, b, l
        float px = f0.x, py = f0.y, rad = f0.w;
        bool keep = (py + rad >= ylo) & (py - rad <= yhi) &
                    (px + rad >= xlo) & (px - rad <= xhi);
        unsigned long long m = __ballot(keep);

        __syncthreads();                       // prior dense loop done with shc/wcnt
        if (lane == 0) wcnt[wid] = __popcll(m);
        __syncthreads();                       // wcnt visible
        int base = 0;
        if (wid > 0) base += wcnt[0];
        if (wid > 1) base += wcnt[1];
        if (wid > 2) base += wcnt[2];
        int total = wcnt[0] + wcnt[1] + wcnt[2] + wcnt[3];
        int pos = base + __popcll(m & ((1ull << lane) - 1ull));
        if (keep) {
            shc[pos * 2]     = make_float4(f0.x, f0.y, f0.z, f1.w);            // px,py,s,l
            shc[pos * 2 + 1] = make_float4(f1.x, f1.y, f1.z, 8.0f * f0.z);     // r,g,b,8s
        }
        __syncthreads();                       // shc visible

        // ---- branch-free dense loop over survivors (broadcast LDS reads) ----
        for (int j = 0; j < total; ++j) {
            float4 a0 = shc[j * 2];
            float4 a1 = shc[j * 2 + 1];
            float s   = a0.z;
            float dx  = a0.x - xf;
            float sdx = s * dx;
            float lm  = __builtin_fmaf(-sdx, sdx, a0.w);   // l - sdx^2
            float sdy = s * (a0.y - y0f);
            float s8  = a1.w;                              // 8s (y-stride 8)
#pragma unroll
            for (int p = 0; p < PPT; ++p) {
                float e = __builtin_fmaf(-sdy, sdy, lm);
                float w = __builtin_amdgcn_exp2f(e);
                nr[p] = __builtin_fmaf(w, a1.x, nr[p]);
                ng[p] = __builtin_fmaf(w, a1.y, ng[p]);
                nb[p] = __builtin_fmaf(w, a1.z, nb[p]);
                nd[p] += w;
                sdy -= s8;
            }
        }
    }

    // ---- plain coalesced partial store (no atomics, no init needed) ----
    float4* pb = partial + ((size_t)gs * 2 + b) * HWP;   // [gs][b][pix]
#pragma unroll
    for (int p = 0; p < PPT; ++p) {
        int y = ytop + yrow + p * 8;
        int pix = y * WW + x;
        pb[pix] = make_float4(nr[p], ng[p], nb[p], nd[p]);
    }
}

__global__ void final_kernel(const float4* __restrict__ partial,
                             float* __restrict__ out, int B, float epsadd) {
    int i = blockIdx.x * blockDim.x + threadIdx.x;   // over B*HW
    if (i >= B * HWP) return;
    int b = i / HWP;
    int p = i - b * HWP;
    float sr = 0.0f, sg = 0.0f, sb = 0.0f, sd = 0.0f;
#pragma unroll 8
    for (int gs = 0; gs < GSPLIT; ++gs) {
        float4 v = partial[((size_t)gs * 2 + b) * HWP + p];
        sr += v.x; sg += v.y; sb += v.z; sd += v.w;
    }
    float den = fmaxf(sd + epsadd, 1e-8f);
    out[(size_t)(b * 3 + 0) * HWP + p] = sr / den;
    out[(size_t)(b * 3 + 1) * HWP + p] = sg / den;
    out[(size_t)(b * 3 + 2) * HWP + p] = sb / den;
}

extern "C" void kernel_launch(void* const* d_in, const int* in_sizes, int n_in,
                              void* d_out, int out_size, void* d_ws, size_t ws_size,
                              hipStream_t stream) {
    const float* pos = (const float*)d_in[0];
    const float* col = (const float*)d_in[1];
    const float* opa = (const float*)d_in[2];
    const float* scl = (const float*)d_in[3];
    const float* qv  = (const float*)d_in[4];
    const float* tv  = (const float*)d_in[5];
    const float* fx  = (const float*)d_in[6];
    const float* fy  = (const float*)d_in[7];
    const float* cx  = (const float*)d_in[8];
    const float* cy  = (const float*)d_in[9];

    int N = in_sizes[0] / 3;
    int B = in_sizes[4] / 4;

    float4* proj    = (float4*)d_ws;
    float4* partial = (float4*)((char*)d_ws + (size_t)B * N * 2 * sizeof(float4));
    float*  outp    = (float*)d_out;

    int tot = N * B;
    proj_kernel<<<(tot + 255) / 256, 256, 0, stream>>>(pos, col, opa, scl, qv, tv,
                                                       fx, fy, cx, cy, proj, N, B);

    int gpb = N / GSPLIT;   // 2048 gaussians per block (8 chunks)
    dim3 grid(GSPLIT, B, NXT * NYB);   // z = (tx, yb-rank) -> per-CU stratified
    accum_kernel<<<grid, 256, 0, stream>>>(proj, partial, N, gpb);

    float epsadd = (float)(N / 2048) * 1e-8f;  // reference adds EPS once per 2048-chunk
    final_kernel<<<(B * HWP + 255) / 256, 256, 0, stream>>>(partial, outp, B, epsadd);
}